// Round 2
// baseline (402.584 us; speedup 1.0000x reference)
//
#include <hip/hip_runtime.h>

// Problem dims (fixed by the reference)
#define R_DIM 64
#define C_DIM 1024
#define B_DIM 2
#define E_DIM 256
#define Q_DIM 256
#define H_DIM 8
#define D_DIM 32
#define ROW_STRIDE ((size_t)C_DIM * B_DIM * E_DIM) /* 524288 floats between r rows */
#define OUT_MAIN ((size_t)R_DIM * C_DIM * B_DIM * E_DIM) /* 33554432 */

typedef short bf16x8 __attribute__((ext_vector_type(8)));
typedef float f32x4 __attribute__((ext_vector_type(4)));

__device__ __forceinline__ unsigned short f2bf(float x) {
  unsigned int u = __builtin_bit_cast(unsigned int, x);
  u += 0x7FFFu + ((u >> 16) & 1u);
  return (unsigned short)(u >> 16);
}

// ---------------------------------------------------------------------------
// prep_q: q[n,e] = (query @ Wq.T + bq)*0.125   (2 blocks x 256 threads)
// ---------------------------------------------------------------------------
__global__ void prep_q(const float* __restrict__ query, const float* __restrict__ Wq,
                       const float* __restrict__ bq, float* __restrict__ q_out) {
  int idx = blockIdx.x * 256 + threadIdx.x; // 0..511
  int n = idx >> 8, e = idx & 255;
  const float4* qr = (const float4*)(query + (size_t)n * Q_DIM);
  const float4* wr = (const float4*)(Wq + (size_t)e * Q_DIM);
  float s = bq[e];
#pragma unroll 8
  for (int k = 0; k < Q_DIM / 4; k++) {
    float4 a = qr[k], b = wr[k];
    s += a.x * b.x + a.y * b.y + a.z * b.z + a.w * b.w;
  }
  q_out[idx] = s * 0.125f; // D^-0.5 / sqrt(B) = 1/8
}

// ---------------------------------------------------------------------------
// prep_w_pack: blocks 0..15 = prep_w (w[h,n,e], bterm), blocks 16..79 = prepack
// (Wv/Wo fp32 -> bf16 MFMA fragment order; same layout serves as A-frag:
//  lane holds W[tile*16 + (lane&15)][kstep*32 + (lane>>4)*8 + j]).
// ---------------------------------------------------------------------------
__global__ void prep_w_pack(const float* __restrict__ q, const float* __restrict__ Wk,
                            const float* __restrict__ bk, float* __restrict__ w_out,
                            float* __restrict__ bterm_out,
                            const float* __restrict__ Wv, const float* __restrict__ Wo,
                            unsigned short* __restrict__ B1p, unsigned short* __restrict__ B2p) {
  if (blockIdx.x < 16) {
    int idx = blockIdx.x * 256 + threadIdx.x; // 0..4095  = ((h*2+n)*256 + e)
    int e2 = idx & 255;
    int hn = idx >> 8;
    int n = hn & 1, h = hn >> 1;
    float s = 0.f;
#pragma unroll
    for (int d = 0; d < D_DIM; d++)
      s += q[n * E_DIM + h * D_DIM + d] * Wk[(h * D_DIM + d) * E_DIM + e2];
    w_out[idx] = s;
    if (idx < H_DIM * B_DIM) {
      int nn = idx & 1, hh = idx >> 1;
      float sb = 0.f;
#pragma unroll
      for (int d = 0; d < D_DIM; d++)
        sb += q[nn * E_DIM + hh * D_DIM + d] * bk[hh * D_DIM + d];
      bterm_out[idx] = sb;
    }
  } else {
    int gidx = (blockIdx.x - 16) * 256 + threadIdx.x; // 0..16383
    const float* src = (gidx < 8192) ? Wv : Wo;
    unsigned short* dst = (gidx < 8192) ? B1p : B2p;
    int li = gidx & 8191;
    int lane = li & 63;
    int pk = li >> 6;
    int ntile = pk >> 3, kstep = pk & 7;
    int row = ntile * 16 + (lane & 15);
    int col0 = kstep * 32 + (lane >> 4) * 8;
    for (int jj = 0; jj < 8; jj++)
      dst[li * 8 + jj] = f2bf(src[row * E_DIM + col0 + jj]);
  }
}

// ---------------------------------------------------------------------------
// scores: block per (j,n). Wave wv reads rows r≡wv (mod 4) as float4/lane
// (1KB contiguous per row), cross-wave LDS reduce, then per-head dot + shuffle.
// ---------------------------------------------------------------------------
__global__ void scores_kernel(const float* __restrict__ key, const float* __restrict__ w,
                              const float* __restrict__ bterm, float* __restrict__ scores) {
  const int bid = blockIdx.x;
  const int j = bid >> 1, n = bid & 1;
  const int t = threadIdx.x;
  const int lane = t & 63, wv = t >> 6;

  const float4* kp = (const float4*)(key + ((size_t)j * B_DIM + n) * E_DIM) + lane;
  float4 ks4 = {0.f, 0.f, 0.f, 0.f};
#pragma unroll
  for (int r = wv; r < R_DIM; r += 4) {
    float4 v = kp[(size_t)r * (ROW_STRIDE / 4)];
    ks4.x += v.x; ks4.y += v.y; ks4.z += v.z; ks4.w += v.w;
  }
  __shared__ float red4[4][E_DIM];
  *(float4*)(&red4[wv][lane * 4]) = ks4;
  __syncthreads();
  float ks = red4[0][t] + red4[1][t] + red4[2][t] + red4[3][t];

  __shared__ float red[H_DIM][4];
  for (int h = 0; h < H_DIM; h++) {
    float p = ks * w[(h * B_DIM + n) * E_DIM + t];
    for (int off = 32; off > 0; off >>= 1) p += __shfl_down(p, off, 64);
    if (lane == 0) red[h][wv] = p;
  }
  __syncthreads();
  if (t < H_DIM) {
    float s = red[t][0] + red[t][1] + red[t][2] + red[t][3] +
              (float)R_DIM * bterm[t * B_DIM + n];
    scores[(t * B_DIM + n) * C_DIM + j] = s;
  }
}

// ---------------------------------------------------------------------------
// softmax over C per (h,n). Writes probs to ws AND to d_out tail.
// ---------------------------------------------------------------------------
__global__ void softmax_kernel(const float* __restrict__ scores, float* __restrict__ probs,
                               float* __restrict__ probs_out) {
  const int hn = blockIdx.x;
  const int t = threadIdx.x;
  const float* s = scores + (size_t)hn * C_DIM;
  float v[4];
  float mx = -1e30f;
  for (int i = 0; i < 4; i++) {
    v[i] = s[t + i * 256];
    mx = fmaxf(mx, v[i]);
  }
  __shared__ float sm[4];
  const int lane = t & 63, wv = t >> 6;
  for (int off = 32; off > 0; off >>= 1) mx = fmaxf(mx, __shfl_down(mx, off, 64));
  if (lane == 0) sm[wv] = mx;
  __syncthreads();
  mx = fmaxf(fmaxf(sm[0], sm[1]), fmaxf(sm[2], sm[3]));
  float sum = 0.f;
  for (int i = 0; i < 4; i++) {
    v[i] = expf(v[i] - mx);
    sum += v[i];
  }
  for (int off = 32; off > 0; off >>= 1) sum += __shfl_down(sum, off, 64);
  __syncthreads();
  if (lane == 0) sm[wv] = sum;
  __syncthreads();
  sum = sm[0] + sm[1] + sm[2] + sm[3];
  float inv = 1.0f / sum;
  for (int i = 0; i < 4; i++) {
    float p = v[i] * inv;
    probs[(size_t)hn * C_DIM + t + i * 256] = p;
    probs_out[(size_t)hn * C_DIM + t + i * 256] = p;
  }
}

// ---------------------------------------------------------------------------
// fused_pv v3: TRANSPOSED GEMMs. Weights are the MFMA A-operand (from L2,
// prepacked); value/vs tiles are the B-operand (from LDS, b128 reads).
//   GEMM1: vs^T[e][vrow]  = Wv[e][c]   x value^T[c][vrow]
//   GEMM2: out^T[f][vrow] = Wo[f][e]   x vs^T[e][vrow]
// D-layout gives each thread 4 CONSECUTIVE e (epilogue1 -> ds_write_b64) and
// 4 consecutive f (epilogue2 -> direct float4 global stores, no otile).
// Wave wv: M-range (e/f) = (wv>>1)*64 (mt=4x16), N-range (vrow) = (wv&1)*32
// (nt=2x16). Two barriers per block; no trailing barrier -> waves drain free.
// LDS: vt (32KB) + vs (32KB) = 64KB -> 2 blocks/CU.
// Rotation col' = (col + 16*((row>>2)&3)) & 255 keeps every LDS access
// pattern (stage b64 writes, b128 frag reads, epilogue1 b64 writes) balanced.
// ---------------------------------------------------------------------------
__global__ __launch_bounds__(512, 4) void fused_pv(
    const float* __restrict__ value, const unsigned short* __restrict__ B1p,
    const unsigned short* __restrict__ B2p, const float* __restrict__ bv,
    const float* __restrict__ bo, const float* __restrict__ probs,
    float* __restrict__ out) {
  __shared__ unsigned short vt[64 * 256]; // bf16 value tile (rotated)
  __shared__ unsigned short vs[64 * 256]; // bf16 vs tile (rotated)
  const int bid = blockIdx.x;
  const int j = bid >> 1, n = bid & 1;
  const int t = threadIdx.x;
  const int lane = t & 63;
  const int wv = t >> 6;      // 0..7
  const int l15 = lane & 15;
  const int quad = lane >> 4;
  const int Mbase = (wv >> 1) * 64; // e/f range base (4 M-groups)
  const int Nbase = (wv & 1) * 32;  // vrow range base (2 N-groups)

  // --- stage value[*, j, n, :] -> bf16 LDS (rotated layout) ---
  const float* vbase = value + ((size_t)j * B_DIM + n) * E_DIM;
#pragma unroll
  for (int row = wv; row < 64; row += 8) {
    const float4 v4 = *(((const float4*)(vbase + (size_t)row * ROW_STRIDE)) + lane);
    ushort4 u;
    u.x = f2bf(v4.x); u.y = f2bf(v4.y); u.z = f2bf(v4.z); u.w = f2bf(v4.w);
    const int col = (lane * 4 + ((row & 12) << 2)) & 255;
    *(ushort4*)(&vt[row * 256 + col]) = u;
  }

  // B-frag row addresses (fixed per nt across ks)
  const int vrow0 = Nbase + l15;
  const int vrow1 = Nbase + 16 + l15;
  const int rot0 = (vrow0 & 12) << 2;
  const int rot1 = (vrow1 & 12) << 2;

  f32x4 acc[4][2]; // [mt][nt]
  const f32x4 zero = {0.f, 0.f, 0.f, 0.f};
#pragma unroll
  for (int mt = 0; mt < 4; mt++)
#pragma unroll
    for (int nt = 0; nt < 2; nt++) acc[mt][nt] = zero;

  __syncthreads(); // S1: value tile staged

  // --- GEMM1: vs^T = Wv x value^T ---
#pragma unroll
  for (int ks = 0; ks < 8; ks++) {
    bf16x8 a[4], b[2];
#pragma unroll
    for (int mt = 0; mt < 4; mt++)
      a[mt] = ((const bf16x8*)B1p)[((((wv >> 1) * 4 + mt) * 8 + ks) * 64 + lane)];
    b[0] = *(const bf16x8*)(&vt[vrow0 * 256 + ((ks * 32 + quad * 8 + rot0) & 255)]);
    b[1] = *(const bf16x8*)(&vt[vrow1 * 256 + ((ks * 32 + quad * 8 + rot1) & 255)]);
#pragma unroll
    for (int mt = 0; mt < 4; mt++)
#pragma unroll
      for (int nt = 0; nt < 2; nt++)
        acc[mt][nt] = __builtin_amdgcn_mfma_f32_16x16x32_bf16(a[mt], b[nt], acc[mt][nt], 0, 0, 0);
  }

  // probs for this wave's two heads (e-range Mbase..Mbase+63 -> heads 2g, 2g+1)
  const float p0 = probs[((size_t)(2 * (wv >> 1)) * B_DIM + n) * C_DIM + j];
  const float p1 = probs[((size_t)(2 * (wv >> 1) + 1) * B_DIM + n) * C_DIM + j];

  // --- epilogue1: vs = (D + bv)*p, bf16, b64 writes (4 consecutive e) ---
#pragma unroll
  for (int mt = 0; mt < 4; mt++) {
    const int e0 = Mbase + mt * 16 + quad * 4;
    const float4 bvv = *(const float4*)(&bv[e0]);
    const float p = (mt < 2) ? p0 : p1; // head = e0>>5 flips at mt==2
#pragma unroll
    for (int nt = 0; nt < 2; nt++) {
      const int vrow = (nt == 0) ? vrow0 : vrow1;
      const int rot = (nt == 0) ? rot0 : rot1;
      ushort4 u;
      u.x = f2bf((acc[mt][nt][0] + bvv.x) * p);
      u.y = f2bf((acc[mt][nt][1] + bvv.y) * p);
      u.z = f2bf((acc[mt][nt][2] + bvv.z) * p);
      u.w = f2bf((acc[mt][nt][3] + bvv.w) * p);
      *(ushort4*)(&vs[vrow * 256 + ((e0 + rot) & 255)]) = u;
      acc[mt][nt] = zero;
    }
  }
  __syncthreads(); // S2: vs tile complete

  // --- GEMM2: out^T = Wo x vs^T ---
#pragma unroll
  for (int ks = 0; ks < 8; ks++) {
    bf16x8 a[4], b[2];
#pragma unroll
    for (int mt = 0; mt < 4; mt++)
      a[mt] = ((const bf16x8*)B2p)[((((wv >> 1) * 4 + mt) * 8 + ks) * 64 + lane)];
    b[0] = *(const bf16x8*)(&vs[vrow0 * 256 + ((ks * 32 + quad * 8 + rot0) & 255)]);
    b[1] = *(const bf16x8*)(&vs[vrow1 * 256 + ((ks * 32 + quad * 8 + rot1) & 255)]);
#pragma unroll
    for (int mt = 0; mt < 4; mt++)
#pragma unroll
      for (int nt = 0; nt < 2; nt++)
        acc[mt][nt] = __builtin_amdgcn_mfma_f32_16x16x32_bf16(a[mt], b[nt], acc[mt][nt], 0, 0, 0);
  }

  // --- epilogue2: +bo, direct float4 stores (4 consecutive f), no barrier ---
  float* obase = out + ((size_t)j * B_DIM + n) * E_DIM;
#pragma unroll
  for (int mt = 0; mt < 4; mt++) {
    const int f0 = Mbase + mt * 16 + quad * 4;
    const float4 bov = *(const float4*)(&bo[f0]);
#pragma unroll
    for (int nt = 0; nt < 2; nt++) {
      const int vrow = (nt == 0) ? vrow0 : vrow1;
      float4 r;
      r.x = acc[mt][nt][0] + bov.x;
      r.y = acc[mt][nt][1] + bov.y;
      r.z = acc[mt][nt][2] + bov.z;
      r.w = acc[mt][nt][3] + bov.w;
      *(float4*)(&obase[(size_t)vrow * ROW_STRIDE + f0]) = r;
    }
  }
}

// ---------------------------------------------------------------------------
extern "C" void kernel_launch(void* const* d_in, const int* in_sizes, int n_in,
                              void* d_out, int out_size, void* d_ws, size_t ws_size,
                              hipStream_t stream) {
  const float* query = (const float*)d_in[0];
  const float* key   = (const float*)d_in[1];
  const float* value = (const float*)d_in[2];
  const float* Wq = (const float*)d_in[3];
  const float* bq = (const float*)d_in[4];
  const float* Wk = (const float*)d_in[5];
  const float* bk = (const float*)d_in[6];
  const float* Wv = (const float*)d_in[7];
  const float* bv = (const float*)d_in[8];
  const float* Wo = (const float*)d_in[9];
  const float* bo = (const float*)d_in[10];
  float* out = (float*)d_out;

  // workspace (floats): w[4096] | bterm[16] | scores[16384] | probs[16384]
  // then bf16: B1p (128KB) | B2p (128KB).  q (512 floats) aliases scores.
  float* ws_f = (float*)d_ws;
  float* w_ = ws_f;
  float* bterm_ = ws_f + 4096;
  float* scores_ = ws_f + 4112;
  float* q_ = scores_; // alias: q dead before scores_kernel writes
  float* probs_ = ws_f + 20496;
  unsigned short* B1p = (unsigned short*)((char*)d_ws + 147520);
  unsigned short* B2p = (unsigned short*)((char*)d_ws + 147520 + 131072);

  prep_q<<<dim3(2), dim3(256), 0, stream>>>(query, Wq, bq, q_);
  prep_w_pack<<<dim3(80), dim3(256), 0, stream>>>(q_, Wk, bk, w_, bterm_, Wv, Wo, B1p, B2p);
  scores_kernel<<<dim3(C_DIM * B_DIM), dim3(256), 0, stream>>>(key, w_, bterm_, scores_);
  softmax_kernel<<<dim3(H_DIM * B_DIM), dim3(256), 0, stream>>>(scores_, probs_,
                                                                out + OUT_MAIN);
  fused_pv<<<dim3(C_DIM * B_DIM), dim3(512), 0, stream>>>(value, B1p, B2p, bv, bo,
                                                          probs_, out);
}

// Round 3
// 391.288 us; speedup vs baseline: 1.0289x; 1.0289x over previous
//
#include <hip/hip_runtime.h>

// Problem dims (fixed by the reference)
#define R_DIM 64
#define C_DIM 1024
#define B_DIM 2
#define E_DIM 256
#define Q_DIM 256
#define H_DIM 8
#define D_DIM 32
#define ROW_STRIDE ((size_t)C_DIM * B_DIM * E_DIM) /* 524288 floats between r rows */
#define OUT_MAIN ((size_t)R_DIM * C_DIM * B_DIM * E_DIM) /* 33554432 */

typedef short bf16x8 __attribute__((ext_vector_type(8)));
typedef float f32x4 __attribute__((ext_vector_type(4)));

__device__ __forceinline__ unsigned short f2bf(float x) {
  unsigned int u = __builtin_bit_cast(unsigned int, x);
  u += 0x7FFFu + ((u >> 16) & 1u);
  return (unsigned short)(u >> 16);
}

// ---------------------------------------------------------------------------
// prep_q: q[n,e] = (query @ Wq.T + bq)*0.125   (2 blocks x 256 threads)
// ---------------------------------------------------------------------------
__global__ void prep_q(const float* __restrict__ query, const float* __restrict__ Wq,
                       const float* __restrict__ bq, float* __restrict__ q_out) {
  int idx = blockIdx.x * 256 + threadIdx.x; // 0..511
  int n = idx >> 8, e = idx & 255;
  const float4* qr = (const float4*)(query + (size_t)n * Q_DIM);
  const float4* wr = (const float4*)(Wq + (size_t)e * Q_DIM);
  float s = bq[e];
#pragma unroll 8
  for (int k = 0; k < Q_DIM / 4; k++) {
    float4 a = qr[k], b = wr[k];
    s += a.x * b.x + a.y * b.y + a.z * b.z + a.w * b.w;
  }
  q_out[idx] = s * 0.125f; // D^-0.5 / sqrt(B) = 1/8
}

// ---------------------------------------------------------------------------
// prep_w_pack: blocks 0..15 = prep_w (w[h,n,e], bterm), blocks 16..79 = prepack
// (Wv/Wo fp32 -> bf16 MFMA fragment order; serves as the A-frag:
//  lane holds W[tile*16 + (lane&15)][kstep*32 + (lane>>4)*8 + j]).
// ---------------------------------------------------------------------------
__global__ void prep_w_pack(const float* __restrict__ q, const float* __restrict__ Wk,
                            const float* __restrict__ bk, float* __restrict__ w_out,
                            float* __restrict__ bterm_out,
                            const float* __restrict__ Wv, const float* __restrict__ Wo,
                            unsigned short* __restrict__ B1p, unsigned short* __restrict__ B2p) {
  if (blockIdx.x < 16) {
    int idx = blockIdx.x * 256 + threadIdx.x; // 0..4095  = ((h*2+n)*256 + e)
    int e2 = idx & 255;
    int hn = idx >> 8;
    int n = hn & 1, h = hn >> 1;
    float s = 0.f;
#pragma unroll
    for (int d = 0; d < D_DIM; d++)
      s += q[n * E_DIM + h * D_DIM + d] * Wk[(h * D_DIM + d) * E_DIM + e2];
    w_out[idx] = s;
    if (idx < H_DIM * B_DIM) {
      int nn = idx & 1, hh = idx >> 1;
      float sb = 0.f;
#pragma unroll
      for (int d = 0; d < D_DIM; d++)
        sb += q[nn * E_DIM + hh * D_DIM + d] * bk[hh * D_DIM + d];
      bterm_out[idx] = sb;
    }
  } else {
    int gidx = (blockIdx.x - 16) * 256 + threadIdx.x; // 0..16383
    const float* src = (gidx < 8192) ? Wv : Wo;
    unsigned short* dst = (gidx < 8192) ? B1p : B2p;
    int li = gidx & 8191;
    int lane = li & 63;
    int pk = li >> 6;
    int ntile = pk >> 3, kstep = pk & 7;
    int row = ntile * 16 + (lane & 15);
    int col0 = kstep * 32 + (lane >> 4) * 8;
    for (int jj = 0; jj < 8; jj++)
      dst[li * 8 + jj] = f2bf(src[row * E_DIM + col0 + jj]);
  }
}

// ---------------------------------------------------------------------------
// scores: block per (j,n). Wave wv reads rows r≡wv (mod 4) as float4/lane
// (1KB contiguous per row), cross-wave LDS reduce, then per-head dot + shuffle.
// ---------------------------------------------------------------------------
__global__ void scores_kernel(const float* __restrict__ key, const float* __restrict__ w,
                              const float* __restrict__ bterm, float* __restrict__ scores) {
  const int bid = blockIdx.x;
  const int j = bid >> 1, n = bid & 1;
  const int t = threadIdx.x;
  const int lane = t & 63, wv = t >> 6;

  const float4* kp = (const float4*)(key + ((size_t)j * B_DIM + n) * E_DIM) + lane;
  float4 ks4 = {0.f, 0.f, 0.f, 0.f};
#pragma unroll
  for (int r = wv; r < R_DIM; r += 4) {
    float4 v = kp[(size_t)r * (ROW_STRIDE / 4)];
    ks4.x += v.x; ks4.y += v.y; ks4.z += v.z; ks4.w += v.w;
  }
  __shared__ float red4[4][E_DIM];
  *(float4*)(&red4[wv][lane * 4]) = ks4;
  __syncthreads();
  float ks = red4[0][t] + red4[1][t] + red4[2][t] + red4[3][t];

  __shared__ float red[H_DIM][4];
  for (int h = 0; h < H_DIM; h++) {
    float p = ks * w[(h * B_DIM + n) * E_DIM + t];
    for (int off = 32; off > 0; off >>= 1) p += __shfl_down(p, off, 64);
    if (lane == 0) red[h][wv] = p;
  }
  __syncthreads();
  if (t < H_DIM) {
    float s = red[t][0] + red[t][1] + red[t][2] + red[t][3] +
              (float)R_DIM * bterm[t * B_DIM + n];
    scores[(t * B_DIM + n) * C_DIM + j] = s;
  }
}

// ---------------------------------------------------------------------------
// softmax over C per (h,n). Writes probs to ws AND to d_out tail.
// ---------------------------------------------------------------------------
__global__ void softmax_kernel(const float* __restrict__ scores, float* __restrict__ probs,
                               float* __restrict__ probs_out) {
  const int hn = blockIdx.x;
  const int t = threadIdx.x;
  const float* s = scores + (size_t)hn * C_DIM;
  float v[4];
  float mx = -1e30f;
  for (int i = 0; i < 4; i++) {
    v[i] = s[t + i * 256];
    mx = fmaxf(mx, v[i]);
  }
  __shared__ float sm[4];
  const int lane = t & 63, wv = t >> 6;
  for (int off = 32; off > 0; off >>= 1) mx = fmaxf(mx, __shfl_down(mx, off, 64));
  if (lane == 0) sm[wv] = mx;
  __syncthreads();
  mx = fmaxf(fmaxf(sm[0], sm[1]), fmaxf(sm[2], sm[3]));
  float sum = 0.f;
  for (int i = 0; i < 4; i++) {
    v[i] = expf(v[i] - mx);
    sum += v[i];
  }
  for (int off = 32; off > 0; off >>= 1) sum += __shfl_down(sum, off, 64);
  __syncthreads();
  if (lane == 0) sm[wv] = sum;
  __syncthreads();
  sum = sm[0] + sm[1] + sm[2] + sm[3];
  float inv = 1.0f / sum;
  for (int i = 0; i < 4; i++) {
    float p = v[i] * inv;
    probs[(size_t)hn * C_DIM + t + i * 256] = p;
    probs_out[(size_t)hn * C_DIM + t + i * 256] = p;
  }
}

// ---------------------------------------------------------------------------
// fused_pv v4 (hybrid): transposed GEMMs (weights = A from L2, tile = B from
// LDS) with v2's occupancy profile.
//   Wave wv owns e/f slice [wv*32, wv*32+32) (mt=2x16, exactly head wv) and
//   ALL 64 vrows (nt=4x16) -> acc[2][4]; A-frags 2/ks (halves v3's L2 frag
//   traffic back to 256KB/block); B-frags 4/ks from LDS.
//   SINGLE 32KB LDS tile, aliased: GEMM1 reads it, barrier, epilogue1
//   overwrites it in place as the vs tile (b64 writes), barrier, GEMM2 reads,
//   epilogue2 stores direct float4 (lanes {l,l+16,l+32,l+48} form 64B rows).
//   3 barriers/block, none trailing. Rotation col'=(col+16*((row>>2)&3))&255
//   keeps stage b64 writes / b128 frag reads / ep1 b64 writes at the bank
//   throughput floor.
// ---------------------------------------------------------------------------
__global__ __launch_bounds__(512, 6) void fused_pv(
    const float* __restrict__ value, const unsigned short* __restrict__ B1p,
    const unsigned short* __restrict__ B2p, const float* __restrict__ bv,
    const float* __restrict__ bo, const float* __restrict__ probs,
    float* __restrict__ out) {
  __shared__ unsigned short tile[64 * 256]; // 32768 B, bf16, rotated layout
  const int bid = blockIdx.x;
  const int j = bid >> 1, n = bid & 1;
  const int t = threadIdx.x;
  const int lane = t & 63;
  const int wv = t >> 6;      // 0..7
  const int l15 = lane & 15;
  const int quad = lane >> 4;

  // probs for this wave's head (e-slice wv*32.. -> head wv); hoisted early
  const float p = probs[((size_t)wv * B_DIM + n) * C_DIM + j];

  // --- stage value[*, j, n, :] -> bf16 LDS (rotated layout) ---
  const float* vbase = value + ((size_t)j * B_DIM + n) * E_DIM;
#pragma unroll
  for (int row = wv; row < 64; row += 8) {
    const float4 v4 = *(((const float4*)(vbase + (size_t)row * ROW_STRIDE)) + lane);
    ushort4 u;
    u.x = f2bf(v4.x); u.y = f2bf(v4.y); u.z = f2bf(v4.z); u.w = f2bf(v4.w);
    const int col = (lane * 4 + ((row & 12) << 2)) & 255;
    *(ushort4*)(&tile[row * 256 + col]) = u;
  }

  const int rot = (l15 & 12) << 2; // row-rotation term, same for every nt

  f32x4 acc[2][4]; // [mt][nt]
  const f32x4 zero = {0.f, 0.f, 0.f, 0.f};
#pragma unroll
  for (int mt = 0; mt < 2; mt++)
#pragma unroll
    for (int nt = 0; nt < 4; nt++) acc[mt][nt] = zero;

  __syncthreads(); // S1: value tile staged

  // --- GEMM1: vs^T = Wv x value^T ---
#pragma unroll
  for (int ks = 0; ks < 8; ks++) {
    bf16x8 a[2], b[4];
#pragma unroll
    for (int mt = 0; mt < 2; mt++)
      a[mt] = ((const bf16x8*)B1p)[((wv * 2 + mt) * 8 + ks) * 64 + lane];
    const int bcol = (ks * 32 + quad * 8 + rot) & 255;
#pragma unroll
    for (int nt = 0; nt < 4; nt++)
      b[nt] = *(const bf16x8*)(&tile[(nt * 16 + l15) * 256 + bcol]);
#pragma unroll
    for (int mt = 0; mt < 2; mt++)
#pragma unroll
      for (int nt = 0; nt < 4; nt++)
        acc[mt][nt] = __builtin_amdgcn_mfma_f32_16x16x32_bf16(a[mt], b[nt], acc[mt][nt], 0, 0, 0);
  }

  __syncthreads(); // S2: all GEMM1 tile reads done before in-place overwrite

  // --- epilogue1: vs = (D + bv)*p, bf16, b64 writes (4 consecutive e) ---
#pragma unroll
  for (int mt = 0; mt < 2; mt++) {
    const int e0 = wv * 32 + mt * 16 + quad * 4;
    const float4 bvv = *(const float4*)(&bv[e0]);
#pragma unroll
    for (int nt = 0; nt < 4; nt++) {
      const int vrow = nt * 16 + l15;
      ushort4 u;
      u.x = f2bf((acc[mt][nt][0] + bvv.x) * p);
      u.y = f2bf((acc[mt][nt][1] + bvv.y) * p);
      u.z = f2bf((acc[mt][nt][2] + bvv.z) * p);
      u.w = f2bf((acc[mt][nt][3] + bvv.w) * p);
      *(ushort4*)(&tile[vrow * 256 + ((e0 + rot) & 255)]) = u;
      acc[mt][nt] = zero;
    }
  }
  __syncthreads(); // S3: vs tile complete

  // --- GEMM2: out^T = Wo x vs^T ---
#pragma unroll
  for (int ks = 0; ks < 8; ks++) {
    bf16x8 a[2], b[4];
#pragma unroll
    for (int mt = 0; mt < 2; mt++)
      a[mt] = ((const bf16x8*)B2p)[((wv * 2 + mt) * 8 + ks) * 64 + lane];
    const int bcol = (ks * 32 + quad * 8 + rot) & 255;
#pragma unroll
    for (int nt = 0; nt < 4; nt++)
      b[nt] = *(const bf16x8*)(&tile[(nt * 16 + l15) * 256 + bcol]);
#pragma unroll
    for (int mt = 0; mt < 2; mt++)
#pragma unroll
      for (int nt = 0; nt < 4; nt++)
        acc[mt][nt] = __builtin_amdgcn_mfma_f32_16x16x32_bf16(a[mt], b[nt], acc[mt][nt], 0, 0, 0);
  }

  // --- epilogue2: +bo, direct float4 stores; lanes {l,l+16,..} give 64B rows ---
  float* obase = out + ((size_t)j * B_DIM + n) * E_DIM;
#pragma unroll
  for (int mt = 0; mt < 2; mt++) {
    const int f0 = wv * 32 + mt * 16 + quad * 4;
    const float4 bov = *(const float4*)(&bo[f0]);
#pragma unroll
    for (int nt = 0; nt < 4; nt++) {
      const int vrow = nt * 16 + l15;
      float4 r;
      r.x = acc[mt][nt][0] + bov.x;
      r.y = acc[mt][nt][1] + bov.y;
      r.z = acc[mt][nt][2] + bov.z;
      r.w = acc[mt][nt][3] + bov.w;
      *(float4*)(&obase[(size_t)vrow * ROW_STRIDE + f0]) = r;
    }
  }
}

// ---------------------------------------------------------------------------
extern "C" void kernel_launch(void* const* d_in, const int* in_sizes, int n_in,
                              void* d_out, int out_size, void* d_ws, size_t ws_size,
                              hipStream_t stream) {
  const float* query = (const float*)d_in[0];
  const float* key   = (const float*)d_in[1];
  const float* value = (const float*)d_in[2];
  const float* Wq = (const float*)d_in[3];
  const float* bq = (const float*)d_in[4];
  const float* Wk = (const float*)d_in[5];
  const float* bk = (const float*)d_in[6];
  const float* Wv = (const float*)d_in[7];
  const float* bv = (const float*)d_in[8];
  const float* Wo = (const float*)d_in[9];
  const float* bo = (const float*)d_in[10];
  float* out = (float*)d_out;

  // workspace (floats): w[4096] | bterm[16] | scores[16384] | probs[16384]
  // then bf16: B1p (128KB) | B2p (128KB).  q (512 floats) aliases scores.
  float* ws_f = (float*)d_ws;
  float* w_ = ws_f;
  float* bterm_ = ws_f + 4096;
  float* scores_ = ws_f + 4112;
  float* q_ = scores_; // alias: q dead before scores_kernel writes
  float* probs_ = ws_f + 20496;
  unsigned short* B1p = (unsigned short*)((char*)d_ws + 147520);
  unsigned short* B2p = (unsigned short*)((char*)d_ws + 147520 + 131072);

  prep_q<<<dim3(2), dim3(256), 0, stream>>>(query, Wq, bq, q_);
  prep_w_pack<<<dim3(80), dim3(256), 0, stream>>>(q_, Wk, bk, w_, bterm_, Wv, Wo, B1p, B2p);
  scores_kernel<<<dim3(C_DIM * B_DIM), dim3(256), 0, stream>>>(key, w_, bterm_, scores_);
  softmax_kernel<<<dim3(H_DIM * B_DIM), dim3(256), 0, stream>>>(scores_, probs_,
                                                                out + OUT_MAIN);
  fused_pv<<<dim3(C_DIM * B_DIM), dim3(512), 0, stream>>>(value, B1p, B2p, bv, bo,
                                                          probs_, out);
}